// Round 13
// baseline (148.589 us; speedup 1.0000x reference)
//
#include <hip/hip_runtime.h>
#include <hip/hip_bf16.h>
#include <stdint.h>

// Int4Linear: out[M,N] = X[M,K] @ W[N,K]^T + bias,  W = (q - zp)*scale
// M = 4096, N = 4096, K = 4096.  fp32 in/out, bf16 MFMA compute.
// GEMM r12: 256x256 tile, BK=64, FOUR waves (2x2), per-wave 128x128 output.
// 1 wave/SIMD -> 512-VGPR budget: acc 256 + all-tile fragments 128 live at
// once; reads/stage/MFMA overlap via intra-wave ILP (compiler lgkmcnt).
// ONE barrier + ONE vmcnt(0) per K-tile. Same LDS layout + XOR swizzle as
// the banked r6 kernel (measured 0 conflicts).
// Banked lessons: 16x16x32 shape only (r11: 32x32 => 1.26e7 conflicts);
// 8-wave/512-thr variant plateaus at 52% MfmaUtil (r3/r6/r10/r12 sweep).

#define MDIM 4096
#define NDIM 4096
#define KDIM 4096
#define BM 256
#define BN 256
#define BK 64
#define NT (KDIM / BK)   // 64 K-tiles

typedef __attribute__((ext_vector_type(8))) short          bf16x8;
typedef __attribute__((ext_vector_type(4))) float          f32x4;
typedef __attribute__((ext_vector_type(8))) unsigned short u16x8;

__device__ __forceinline__ unsigned short f32_bf16_rne(float f) {
  union { float f; unsigned u; } v; v.f = f;
  return (unsigned short)((v.u + 0x7FFFu + ((v.u >> 16) & 1u)) >> 16);
}

// ---- fused converter, 16384 blocks x 256 thr:
//      blocks [0,8192)      : x fp32 -> bf16
//      blocks [8192,16384)  : W int32 -> bf16  (dequant (q-zp)*scale) ----
__global__ __launch_bounds__(256) void cvt_fused_kernel(const float* __restrict__ x,
                                                        unsigned short* __restrict__ xb,
                                                        const int* __restrict__ q,
                                                        const float* __restrict__ scale,
                                                        const int* __restrict__ zp,
                                                        unsigned short* __restrict__ wb) {
  int b = blockIdx.x;
  if (b < 8192) {
    int i = b * 256 + threadIdx.x;
    const f32x4* p = (const f32x4*)x + (size_t)i * 2;
    f32x4 a = p[0], c = p[1];
    u16x8 o;
    o[0] = f32_bf16_rne(a[0]); o[1] = f32_bf16_rne(a[1]);
    o[2] = f32_bf16_rne(a[2]); o[3] = f32_bf16_rne(a[3]);
    o[4] = f32_bf16_rne(c[0]); o[5] = f32_bf16_rne(c[1]);
    o[6] = f32_bf16_rne(c[2]); o[7] = f32_bf16_rne(c[3]);
    *((u16x8*)xb + i) = o;
  } else {
    int i = (b - 8192) * 256 + threadIdx.x;
    int o = i >> 9;
    float s = scale[o];
    float z = (float)zp[o];
    const int4* p = (const int4*)q + (size_t)i * 2;
    int4 a = p[0], c = p[1];
    u16x8 r;
    r[0] = f32_bf16_rne(((float)a.x - z) * s);
    r[1] = f32_bf16_rne(((float)a.y - z) * s);
    r[2] = f32_bf16_rne(((float)a.z - z) * s);
    r[3] = f32_bf16_rne(((float)a.w - z) * s);
    r[4] = f32_bf16_rne(((float)c.x - z) * s);
    r[5] = f32_bf16_rne(((float)c.y - z) * s);
    r[6] = f32_bf16_rne(((float)c.z - z) * s);
    r[7] = f32_bf16_rne(((float)c.w - z) * s);
    *((u16x8*)wb + i) = r;
  }
}

#define BAR() { asm volatile("" ::: "memory"); __builtin_amdgcn_s_barrier(); asm volatile("" ::: "memory"); }

// LDS map (byte offsets into 128 KiB):
//   A: (buf*2 + half) * 16384            [0, 64K)
//   B: 65536 + (buf*2 + half) * 16384    [64K, 128K)
// half-tile = 128 rows x 64 bf16 = 16 KiB. Swizzle involution on byte offset
// within a half-tile: o ^= ((o>>7)&7)<<4.
__global__ __launch_bounds__(256, 1) void gemm_kernel(const unsigned short* __restrict__ A,
                                                      const unsigned short* __restrict__ B,
                                                      const float* __restrict__ bias,
                                                      float* __restrict__ C) {
  __shared__ __align__(16) char lds[131072];

  // XCD-bijective swizzle: nwg = 256, divisible by 8
  int bid = (int)blockIdx.x;
  int wg  = (bid & 7) * 32 + (bid >> 3);
  int bm  = wg >> 4;                // 16 tiles per row
  int bn  = wg & 15;

  const int tid  = threadIdx.x;
  const int lane = tid & 63;
  const int wv   = tid >> 6;        // 0..3
  const int wm2  = wv >> 1;         // A half this wave owns (M)
  const int wn2  = wv & 1;          // B half this wave owns (N)
  const int lr   = lane & 15;
  const int kg   = lane >> 4;       // 0..3

  const size_t rowA0 = (size_t)bm * BM;
  const size_t rowB0 = (size_t)bn * BN;

  f32x4 acc[8][8];                  // 256 VGPRs
#pragma unroll
  for (int fm = 0; fm < 8; ++fm)
#pragma unroll
    for (int fn = 0; fn < 8; ++fn) acc[fm][fn] = (f32x4)0.f;

  bf16x8 aF[2][8];                  // [ks][fm]  64 VGPRs
  bf16x8 bF[2][8];                  // [ks][fn]  64 VGPRs

  // stage one half-tile: 256 thr x 4 x global_load_lds(16B) = 16 KiB
  auto stage = [&](const unsigned short* G, size_t row0, int kt, int half, int matBase) {
    int ldsBase = matBase + ((kt & 1) * 2 + half) * 16384;
#pragma unroll
    for (int i = 0; i < 4; ++i) {
      int L  = tid * 16 + i * 4096;
      int o  = L ^ (((L >> 7) & 7) << 4);
      int r  = o >> 7;
      int cb = o & 127;
      const char* src = (const char*)G +
          ((row0 + half * 128 + r) * (size_t)KDIM + (size_t)kt * BK) * 2 + cb;
      __builtin_amdgcn_global_load_lds((const __attribute__((address_space(1))) void*)src,
                                       (__attribute__((address_space(3))) void*)(lds + ldsBase + L),
                                       16, 0, 0);
    }
  };

  auto ldsA = [&](int cur, int fm, int ks) -> bf16x8 {
    int ra  = fm * 16 + lr;
    int off = (ra << 7) + ks * 64 + kg * 16;
    off ^= (ra & 7) << 4;
    return *(const bf16x8*)(lds + (cur * 2 + wm2) * 16384 + off);
  };
  auto ldsB = [&](int cur, int fn, int ks) -> bf16x8 {
    int rb  = fn * 16 + lr;
    int off = (rb << 7) + ks * 64 + kg * 16;
    off ^= (rb & 7) << 4;
    return *(const bf16x8*)(lds + 65536 + (cur * 2 + wn2) * 16384 + off);
  };

  // ---- prologue: stage K0 fully; drain; barrier ----
  stage(A, rowA0, 0, 0, 0);
  stage(A, rowA0, 0, 1, 0);
  stage(B, rowB0, 0, 0, 65536);
  stage(B, rowB0, 0, 1, 65536);
  asm volatile("s_waitcnt vmcnt(0)" ::: "memory");
  BAR();

  // ---- main loop: one barrier + one vmcnt per K-tile ----
  for (int u = 0; u < NT; ++u) {
    int cur = u & 1;

    // issue all 32 fragment reads (lgkm; compiler fine-grains waits)
#pragma unroll
    for (int ks = 0; ks < 2; ++ks)
#pragma unroll
      for (int fm = 0; fm < 8; ++fm) aF[ks][fm] = ldsA(cur, fm, ks);
#pragma unroll
    for (int ks = 0; ks < 2; ++ks)
#pragma unroll
      for (int fn = 0; fn < 8; ++fn) bF[ks][fn] = ldsB(cur, fn, ks);

    // issue next tile's staging (vm; drained after the MFMA block)
    if (u + 1 < NT) {
      stage(A, rowA0, u + 1, 0, 0);
      stage(A, rowA0, u + 1, 1, 0);
      stage(B, rowB0, u + 1, 0, 65536);
      stage(B, rowB0, u + 1, 1, 65536);
    }

    // 128 MFMA; acc reuse distance 64 -> fully pipelined
    __builtin_amdgcn_s_setprio(1);
#pragma unroll
    for (int ks = 0; ks < 2; ++ks)
#pragma unroll
      for (int fm = 0; fm < 8; ++fm)
#pragma unroll
        for (int fn = 0; fn < 8; ++fn)
          acc[fm][fn] = __builtin_amdgcn_mfma_f32_16x16x32_bf16(
              aF[ks][fm], bF[ks][fn], acc[fm][fn], 0, 0, 0);
    __builtin_amdgcn_s_setprio(0);

    asm volatile("s_waitcnt vmcnt(0)" ::: "memory");   // ~free: loads flew under MFMA
    BAR();
  }

  // ---- epilogue: D col = lane&15, row = (lane>>4)*4 + reg; add bias ----
  const size_t crow0 = rowA0 + (size_t)wm2 * 128;
  const size_t ccol0 = rowB0 + (size_t)wn2 * 128;
#pragma unroll
  for (int fn = 0; fn < 8; ++fn) {
    size_t col = ccol0 + fn * 16 + lr;
    float bv = bias[col];
#pragma unroll
    for (int fm = 0; fm < 8; ++fm) {
      size_t row = crow0 + fm * 16 + kg * 4;
#pragma unroll
      for (int r = 0; r < 4; ++r)
        C[(row + r) * NDIM + col] = acc[fm][fn][r] + bv;
    }
  }
}

extern "C" void kernel_launch(void* const* d_in, const int* in_sizes, int n_in,
                              void* d_out, int out_size, void* d_ws, size_t ws_size,
                              hipStream_t stream) {
  const float* x     = (const float*)d_in[0];
  const int*   qw    = (const int*)d_in[1];
  const float* scale = (const float*)d_in[2];
  const int*   zp    = (const int*)d_in[3];
  const float* bias  = (const float*)d_in[4];
  float* out = (float*)d_out;

  unsigned short* xb = (unsigned short*)d_ws;            // 32 MiB
  unsigned short* wb = xb + (size_t)MDIM * KDIM;         // +32 MiB

  cvt_fused_kernel<<<16384, 256, 0, stream>>>(x, xb, qw, scale, zp, wb);
  gemm_kernel<<<(MDIM / BM) * (NDIM / BN), 256, 0, stream>>>(xb, wb, bias, out);
}

// Round 14
// 144.440 us; speedup vs baseline: 1.0287x; 1.0287x over previous
//
#include <hip/hip_runtime.h>
#include <hip/hip_bf16.h>
#include <stdint.h>

// Int4Linear: out[M,N] = X[M,K] @ W[N,K]^T + bias,  W = (q - zp)*scale
// M = 4096, N = 4096, K = 4096.  fp32 in/out, bf16 MFMA compute.
// GEMM: r6 banked schedule — 256x256 tile, BK=64, 8 waves (2M x 4N),
// 4 windows/K-tile, ONE barrier per window, counted vmcnt(4), LDS XOR
// swizzle, setprio, ks-outer MFMA.  Epilogue r14: paired fn-stores so both
// 64B halves of each 128B C line issue back-to-back (full-line writeback).
// Banked lessons: 16x16x32 shape only (r11: 32x32 => 1.26e7 conflicts);
// frag live-set <= 80 VGPR (r7: spill => vmcnt pollution); barrier sweep
// 8/4/2 per tile = 42.8/52.5/51% MfmaUtil (keep 4); 4-wave/1-per-SIMD
// exposes serial latency (r13: 46%).

#define MDIM 4096
#define NDIM 4096
#define KDIM 4096
#define BM 256
#define BN 256
#define BK 64
#define NT (KDIM / BK)   // 64 K-tiles

typedef __attribute__((ext_vector_type(8))) short          bf16x8;
typedef __attribute__((ext_vector_type(4))) float          f32x4;
typedef __attribute__((ext_vector_type(8))) unsigned short u16x8;

__device__ __forceinline__ unsigned short f32_bf16_rne(float f) {
  union { float f; unsigned u; } v; v.f = f;
  return (unsigned short)((v.u + 0x7FFFu + ((v.u >> 16) & 1u)) >> 16);
}

// ---- fused converter, 16384 blocks x 256 thr:
//      blocks [0,8192)      : x fp32 -> bf16
//      blocks [8192,16384)  : W int32 -> bf16  (dequant (q-zp)*scale) ----
__global__ __launch_bounds__(256) void cvt_fused_kernel(const float* __restrict__ x,
                                                        unsigned short* __restrict__ xb,
                                                        const int* __restrict__ q,
                                                        const float* __restrict__ scale,
                                                        const int* __restrict__ zp,
                                                        unsigned short* __restrict__ wb) {
  int b = blockIdx.x;
  if (b < 8192) {
    int i = b * 256 + threadIdx.x;
    const f32x4* p = (const f32x4*)x + (size_t)i * 2;
    f32x4 a = p[0], c = p[1];
    u16x8 o;
    o[0] = f32_bf16_rne(a[0]); o[1] = f32_bf16_rne(a[1]);
    o[2] = f32_bf16_rne(a[2]); o[3] = f32_bf16_rne(a[3]);
    o[4] = f32_bf16_rne(c[0]); o[5] = f32_bf16_rne(c[1]);
    o[6] = f32_bf16_rne(c[2]); o[7] = f32_bf16_rne(c[3]);
    *((u16x8*)xb + i) = o;
  } else {
    int i = (b - 8192) * 256 + threadIdx.x;
    int o = i >> 9;
    float s = scale[o];
    float z = (float)zp[o];
    const int4* p = (const int4*)q + (size_t)i * 2;
    int4 a = p[0], c = p[1];
    u16x8 r;
    r[0] = f32_bf16_rne(((float)a.x - z) * s);
    r[1] = f32_bf16_rne(((float)a.y - z) * s);
    r[2] = f32_bf16_rne(((float)a.z - z) * s);
    r[3] = f32_bf16_rne(((float)a.w - z) * s);
    r[4] = f32_bf16_rne(((float)c.x - z) * s);
    r[5] = f32_bf16_rne(((float)c.y - z) * s);
    r[6] = f32_bf16_rne(((float)c.z - z) * s);
    r[7] = f32_bf16_rne(((float)c.w - z) * s);
    *((u16x8*)wb + i) = r;
  }
}

#define BAR() { asm volatile("" ::: "memory"); __builtin_amdgcn_s_barrier(); asm volatile("" ::: "memory"); }

// ks OUTER: the 8 MFMAs of ks=0 are mutually independent; the dependent
// accumulator re-use (ks=1) is 8 instructions away -> fully pipelined.
#define MFMA_Q(MH, NH)                                                          \
  { __builtin_amdgcn_s_setprio(1);                                              \
    _Pragma("unroll") for (int ks = 0; ks < 2; ++ks)                            \
    _Pragma("unroll") for (int fm = 0; fm < 4; ++fm)                            \
    _Pragma("unroll") for (int fn = 0; fn < 2; ++fn)                            \
      acc[MH][NH][fm][fn] = __builtin_amdgcn_mfma_f32_16x16x32_bf16(            \
          aR[MH][fm][ks], bR[fn][ks], acc[MH][NH][fm][fn], 0, 0, 0);            \
    __builtin_amdgcn_s_setprio(0); }

// LDS map (byte offsets into 128 KiB):
//   A: (buf*2 + half) * 16384            [0, 64K)
//   B: 65536 + (buf*2 + half) * 16384    [64K, 128K)
// half-tile = 128 rows x 64 bf16 = 16 KiB. Swizzle involution on byte offset
// within a half-tile: o ^= ((o>>7)&7)<<4.
__global__ __launch_bounds__(512, 2) void gemm_kernel(const unsigned short* __restrict__ A,
                                                      const unsigned short* __restrict__ B,
                                                      const float* __restrict__ bias,
                                                      float* __restrict__ C) {
  __shared__ __align__(16) char lds[131072];

  // XCD-bijective swizzle: nwg = 256, divisible by 8
  int bid = (int)blockIdx.x;
  int wg  = (bid & 7) * 32 + (bid >> 3);
  int bm  = wg >> 4;                // 16 tiles per row
  int bn  = wg & 15;

  const int tid   = threadIdx.x;
  const int lane  = tid & 63;
  const int wv    = tid >> 6;       // 0..7
  const int wm    = wv >> 2;        // 0..1
  const int wn    = wv & 3;         // 0..3
  const int lr    = lane & 15;
  const int kg    = lane >> 4;      // 0..3
  const int bhalf = wn >> 1;        // B half-tile this wave reads
  const int brow0 = (wn & 1) * 64;  // local row base within that B half

  const size_t rowA0 = (size_t)bm * BM;
  const size_t rowB0 = (size_t)bn * BN;

  f32x4 acc[2][2][4][2];            // [mh][nh][fm][fn]
#pragma unroll
  for (int a = 0; a < 2; ++a)
#pragma unroll
    for (int b = 0; b < 2; ++b)
#pragma unroll
      for (int c = 0; c < 4; ++c)
#pragma unroll
        for (int d = 0; d < 2; ++d) acc[a][b][c][d] = (f32x4)0.f;

  bf16x8 aR[2][4][2];               // [mh][fm][ks]
  bf16x8 bR[2][2];                  // [fn][ks]

  auto stage = [&](const unsigned short* G, size_t row0, int kt, int half, int matBase) {
    int ldsBase = matBase + ((kt & 1) * 2 + half) * 16384;
#pragma unroll
    for (int i = 0; i < 2; ++i) {
      int L  = tid * 16 + i * 8192;
      int o  = L ^ (((L >> 7) & 7) << 4);
      int r  = o >> 7;
      int cb = o & 127;
      const char* src = (const char*)G +
          ((row0 + half * 128 + r) * (size_t)KDIM + (size_t)kt * BK) * 2 + cb;
      __builtin_amdgcn_global_load_lds((const __attribute__((address_space(1))) void*)src,
                                       (__attribute__((address_space(3))) void*)(lds + ldsBase + L),
                                       16, 0, 0);
    }
  };

  auto ldsA = [&](int cur, int mh, int fm, int ks) -> bf16x8 {
    int ra  = mh * 64 + fm * 16 + lr;
    int off = (ra << 7) + ks * 64 + kg * 16;
    off ^= (ra & 7) << 4;
    return *(const bf16x8*)(lds + (cur * 2 + wm) * 16384 + off);
  };
  auto ldsB = [&](int cur, int nh, int fn, int ks) -> bf16x8 {
    int rb  = brow0 + nh * 32 + fn * 16 + lr;
    int off = (rb << 7) + ks * 64 + kg * 16;
    off ^= (rb & 7) << 4;
    return *(const bf16x8*)(lds + 65536 + (cur * 2 + bhalf) * 16384 + off);
  };

  // ---- prologue: K0 fully + A-halves of K1; drain K0 (oldest 8 of 12) ----
  stage(A, rowA0, 0, 0, 0);
  stage(A, rowA0, 0, 1, 0);
  stage(B, rowB0, 0, 0, 65536);
  stage(B, rowB0, 0, 1, 65536);
  stage(A, rowA0, 1, 0, 0);
  stage(A, rowA0, 1, 1, 0);
  asm volatile("s_waitcnt vmcnt(4)" ::: "memory");
  BAR();

  // ---- main loop: 4 windows per K-tile, ONE barrier per window ----
  for (int u = 0; u < NT; ++u) {
    int cur = u & 1;

    // Q1 (mh=0,nh=0): reads A.h0 (8) + B.h0 (4) ks-major; stage B.h0(u+1)
#pragma unroll
    for (int ks = 0; ks < 2; ++ks) {
#pragma unroll
      for (int fm = 0; fm < 4; ++fm) aR[0][fm][ks] = ldsA(cur, 0, fm, ks);
#pragma unroll
      for (int fn = 0; fn < 2; ++fn) bR[fn][ks] = ldsB(cur, 0, fn, ks);
    }
    if (u + 1 < NT) stage(B, rowB0, u + 1, 0, 65536);
    BAR(); MFMA_Q(0, 0);

    // Q2 (mh=1,nh=0): reads A.h1 (8); stage B.h1(u+1)
#pragma unroll
    for (int ks = 0; ks < 2; ++ks)
#pragma unroll
      for (int fm = 0; fm < 4; ++fm) aR[1][fm][ks] = ldsA(cur, 1, fm, ks);
    if (u + 1 < NT) stage(B, rowB0, u + 1, 1, 65536);
    BAR(); MFMA_Q(1, 0);

    // Q3 (mh=1,nh=1): reads B.h1 (4); stage A.h0(u+2)
#pragma unroll
    for (int ks = 0; ks < 2; ++ks)
#pragma unroll
      for (int fn = 0; fn < 2; ++fn) bR[fn][ks] = ldsB(cur, 1, fn, ks);
    if (u + 2 < NT) stage(A, rowA0, u + 2, 0, 0);
    BAR(); MFMA_Q(1, 1);

    // Q4 (mh=0,nh=1): no reads; stage A.h1(u+2); counted vmcnt once per tile
    if (u + 2 < NT) stage(A, rowA0, u + 2, 1, 0);
    if (u < NT - 2)       { asm volatile("s_waitcnt vmcnt(4)" ::: "memory"); }
    else if (u == NT - 2) { asm volatile("s_waitcnt vmcnt(0)" ::: "memory"); }
    BAR(); MFMA_Q(0, 1);
  }

  // ---- epilogue: D col = lane&15, row = (lane>>4)*4 + reg; add bias.
  // r14: fn innermost per row so both 64B halves of each 128B line issue
  // back-to-back -> full-line writeback (WRITE_SIZE 88 -> ~67 MB). ----
  const size_t crow0 = rowA0 + (size_t)wm * 128;
  const size_t ccol0 = rowB0 + (size_t)wn * 64;
#pragma unroll
  for (int nh = 0; nh < 2; ++nh) {
    size_t col0 = ccol0 + nh * 32 + lr;
    size_t col1 = col0 + 16;
    float bv0 = bias[col0];
    float bv1 = bias[col1];
#pragma unroll
    for (int mh = 0; mh < 2; ++mh)
#pragma unroll
      for (int fm = 0; fm < 4; ++fm) {
        size_t row = crow0 + mh * 64 + fm * 16 + kg * 4;
#pragma unroll
        for (int r = 0; r < 4; ++r) {
          float* line = C + (row + r) * NDIM;
          line[col0] = acc[mh][nh][fm][0][r] + bv0;
          line[col1] = acc[mh][nh][fm][1][r] + bv1;
        }
      }
  }
}

extern "C" void kernel_launch(void* const* d_in, const int* in_sizes, int n_in,
                              void* d_out, int out_size, void* d_ws, size_t ws_size,
                              hipStream_t stream) {
  const float* x     = (const float*)d_in[0];
  const int*   qw    = (const int*)d_in[1];
  const float* scale = (const float*)d_in[2];
  const int*   zp    = (const int*)d_in[3];
  const float* bias  = (const float*)d_in[4];
  float* out = (float*)d_out;

  unsigned short* xb = (unsigned short*)d_ws;            // 32 MiB
  unsigned short* wb = xb + (size_t)MDIM * KDIM;         // +32 MiB

  cvt_fused_kernel<<<16384, 256, 0, stream>>>(x, xb, qw, scale, zp, wb);
  gemm_kernel<<<(MDIM / BM) * (NDIM / BN), 512, 0, stream>>>(xb, wb, bias, out);
}